// Round 1
// baseline (1083.906 us; speedup 1.0000x reference)
//
#include <hip/hip_runtime.h>
#include <hip/hip_bf16.h>

#define IN_DIM 784
#define HIDDEN 1024
#define OUT_DIM 10
#define BATCH 256

// ---------------------------------------------------------------------------
// K1: transpose x [256][784] -> xT [784][256] so layer-1 reads are coalesced
// over batch (matching mask's innermost dim).
// ---------------------------------------------------------------------------
__global__ __launch_bounds__(256) void k_transpose_x(
    const float* __restrict__ x, float* __restrict__ xT)
{
    const int i = blockIdx.x;    // 0..783
    const int b = threadIdx.x;   // 0..255
    xT[i * BATCH + b] = x[b * IN_DIM + i];
}

// ---------------------------------------------------------------------------
// K2: DropConnect layer 1 (the HBM-bound kernel).
//   h1T[h][b] = relu(b1[h] + sum_i W1[h,i] * mask[h,i,b] * x[b,i])
// One block per h. 256 threads = 64 b-groups (float4 over batch) x 4 i-phases.
// mask reads: lane bg reads float4 at (h*784+i)*256 + 4*bg -> contiguous
// 1 KB per wave, 4 consecutive rows per block iteration = pure streaming.
// ---------------------------------------------------------------------------
__global__ __launch_bounds__(256) void k_layer1(
    const float* __restrict__ W1, const float* __restrict__ mask,
    const float* __restrict__ xT, const float* __restrict__ b1,
    float* __restrict__ h1T)
{
    const int h  = blockIdx.x;       // 0..1023
    const int t  = threadIdx.x;
    const int bg = t & 63;           // batch group: b = 4*bg .. 4*bg+3
    const int is = t >> 6;           // i phase 0..3 (wave-uniform)

    const float4* __restrict__ mask4 =
        (const float4*)(mask + (size_t)h * (IN_DIM * BATCH));
    const float4* __restrict__ xT4 = (const float4*)xT;
    const float* __restrict__ w1row = W1 + h * IN_DIM;

    float4 acc = make_float4(0.f, 0.f, 0.f, 0.f);
    #pragma unroll 4
    for (int i = is; i < IN_DIM; i += 4) {
        const float  w = w1row[i];           // wave-uniform
        const float4 m = mask4[i * 64 + bg]; // HBM stream
        const float4 xv = xT4[i * 64 + bg];  // L2-resident
        acc.x = fmaf(w, m.x * xv.x, acc.x);
        acc.y = fmaf(w, m.y * xv.y, acc.y);
        acc.z = fmaf(w, m.z * xv.z, acc.z);
        acc.w = fmaf(w, m.w * xv.w, acc.w);
    }

    __shared__ float4 red[4][64];
    red[is][bg] = acc;
    __syncthreads();
    if (is == 0) {
        const float4 s0 = red[0][bg], s1 = red[1][bg];
        const float4 s2 = red[2][bg], s3 = red[3][bg];
        const float bias = b1[h];
        float4 r;
        r.x = fmaxf(s0.x + s1.x + s2.x + s3.x + bias, 0.f);
        r.y = fmaxf(s0.y + s1.y + s2.y + s3.y + bias, 0.f);
        r.z = fmaxf(s0.z + s1.z + s2.z + s3.z + bias, 0.f);
        r.w = fmaxf(s0.w + s1.w + s2.w + s3.w + bias, 0.f);
        ((float4*)h1T)[h * 64 + bg] = r;     // h1T[h][4*bg..4*bg+3]
    }
}

// ---------------------------------------------------------------------------
// K3: layer 2 GEMM: h2[b][j] = relu(b2[j] + sum_h h1T[h][b] * W2[j][h])
// 32x32 output tile per block, 256 blocks (8 b-tiles x 32 j-tiles),
// 256 threads, 4 outputs per thread (4 consecutive b, 1 j).
// ---------------------------------------------------------------------------
__global__ __launch_bounds__(256) void k_layer2(
    const float* __restrict__ h1T, const float* __restrict__ W2,
    const float* __restrict__ b2, float* __restrict__ h2)
{
    const int t  = threadIdx.x;
    const int jj = t & 31;          // j within tile
    const int bg = t >> 5;          // 0..7 -> b = b0 + 4*bg + c
    const int b0 = blockIdx.x * 32;
    const int j0 = blockIdx.y * 32;

    __shared__ __align__(16) float Ash[32][32];   // [hh][bb] from h1T
    __shared__ float Bsh[32][33];                 // [hh][jj] from W2 (padded)

    float acc0 = 0.f, acc1 = 0.f, acc2 = 0.f, acc3 = 0.f;

    for (int h0 = 0; h0 < HIDDEN; h0 += 32) {
        // stage A: Ash[hh][bb] = h1T[(h0+hh)*256 + b0+bb]
        #pragma unroll
        for (int r = 0; r < 4; r++) {
            const int idx = t + r * 256;
            const int hh = idx >> 5, bb = idx & 31;
            Ash[hh][bb] = h1T[(h0 + hh) * BATCH + b0 + bb];
        }
        // stage B: Bsh[hh][jj] = W2[(j0+jj)*1024 + h0+hh]
        #pragma unroll
        for (int r = 0; r < 4; r++) {
            const int idx = t + r * 256;
            const int jl = idx >> 5, hl = idx & 31;
            Bsh[hl][jl] = W2[(j0 + jl) * HIDDEN + h0 + hl];
        }
        __syncthreads();
        #pragma unroll 8
        for (int hh = 0; hh < 32; hh++) {
            const float w = Bsh[hh][jj];                     // stride-33: conflict-free
            const float4 a = *(const float4*)&Ash[hh][bg * 4]; // half-wave broadcast
            acc0 = fmaf(a.x, w, acc0);
            acc1 = fmaf(a.y, w, acc1);
            acc2 = fmaf(a.z, w, acc2);
            acc3 = fmaf(a.w, w, acc3);
        }
        __syncthreads();
    }

    const float bias = b2[j0 + jj];
    const int base = (b0 + bg * 4) * HIDDEN + j0 + jj;
    h2[base + 0 * HIDDEN] = fmaxf(acc0 + bias, 0.f);
    h2[base + 1 * HIDDEN] = fmaxf(acc1 + bias, 0.f);
    h2[base + 2 * HIDDEN] = fmaxf(acc2 + bias, 0.f);
    h2[base + 3 * HIDDEN] = fmaxf(acc3 + bias, 0.f);
}

// ---------------------------------------------------------------------------
// K4: layer 3: out[b][o] = b3[o] + sum_h h2[b][h] * W3[o][h]
// One block per sample b; h2 row staged in LDS; shuffle reduction.
// ---------------------------------------------------------------------------
__global__ __launch_bounds__(256) void k_layer3(
    const float* __restrict__ h2, const float* __restrict__ W3,
    const float* __restrict__ b3, float* __restrict__ out)
{
    const int b = blockIdx.x;
    const int t = threadIdx.x;
    const int lane = t & 63, wid = t >> 6;

    __shared__ float hbuf[HIDDEN];
    #pragma unroll
    for (int r = 0; r < 4; r++)
        hbuf[t + r * 256] = h2[b * HIDDEN + t + r * 256];
    __syncthreads();

    float acc[OUT_DIM];
    #pragma unroll
    for (int o = 0; o < OUT_DIM; o++) acc[o] = 0.f;

    for (int h = t; h < HIDDEN; h += 256) {
        const float v = hbuf[h];
        #pragma unroll
        for (int o = 0; o < OUT_DIM; o++)
            acc[o] = fmaf(v, W3[o * HIDDEN + h], acc[o]);
    }

    __shared__ float red[4][OUT_DIM];
    #pragma unroll
    for (int o = 0; o < OUT_DIM; o++) {
        float v = acc[o];
        for (int off = 32; off > 0; off >>= 1)
            v += __shfl_down(v, off);
        if (lane == 0) red[wid][o] = v;
    }
    __syncthreads();
    if (t < OUT_DIM) {
        out[b * OUT_DIM + t] =
            red[0][t] + red[1][t] + red[2][t] + red[3][t] + b3[t];
    }
}

extern "C" void kernel_launch(void* const* d_in, const int* in_sizes, int n_in,
                              void* d_out, int out_size, void* d_ws, size_t ws_size,
                              hipStream_t stream) {
    const float* x    = (const float*)d_in[0];
    const float* mask = (const float*)d_in[1];
    const float* W1   = (const float*)d_in[2];
    const float* b1   = (const float*)d_in[3];
    const float* W2   = (const float*)d_in[4];
    const float* b2   = (const float*)d_in[5];
    const float* W3   = (const float*)d_in[6];
    const float* b3   = (const float*)d_in[7];
    float* out = (float*)d_out;

    float* ws  = (float*)d_ws;
    float* xT  = ws;                              // 784*256   = 200704
    float* h1T = xT + IN_DIM * BATCH;             // 1024*256  = 262144
    float* h2  = h1T + HIDDEN * BATCH;            // 256*1024  = 262144

    k_transpose_x<<<IN_DIM, 256, 0, stream>>>(x, xT);
    k_layer1<<<HIDDEN, 256, 0, stream>>>(W1, mask, xT, b1, h1T);
    k_layer2<<<dim3(BATCH / 32, HIDDEN / 32), 256, 0, stream>>>(h1T, W2, b2, h2);
    k_layer3<<<BATCH, 256, 0, stream>>>(h2, W3, b3, out);
}

// Round 2
// 1051.443 us; speedup vs baseline: 1.0309x; 1.0309x over previous
//
#include <hip/hip_runtime.h>
#include <hip/hip_bf16.h>

#define IN_DIM 784
#define HIDDEN 1024
#define OUT_DIM 10
#define BATCH 256

// layer-1 split-K tiling
#define C_I 49        // i-chunk size (784 = 16 * 49)
#define N_CH 16       // number of i-chunks
#define H_T 32        // h-tile per block

typedef float __attribute__((ext_vector_type(4))) f32x4;

// ---------------------------------------------------------------------------
// K1: transpose x [256][784] -> xT [784][256] (coalesced writes).
// ---------------------------------------------------------------------------
__global__ __launch_bounds__(256) void k_transpose_x(
    const float* __restrict__ x, float* __restrict__ xT)
{
    const int i = blockIdx.x;    // 0..783
    const int b = threadIdx.x;   // 0..255
    xT[i * BATCH + b] = x[b * IN_DIM + i];
}

// ---------------------------------------------------------------------------
// K2: DropConnect layer 1, split-K over i.
// Block (ht, c): h in [32*ht, 32*ht+32), i in [49*c, 49*c+49), all 256 b.
// x-chunk (50 KB) + W1 tile (6 KB) staged in LDS -> xT re-read traffic
// drops from 822 MB (cache-thrashed to HBM) to 26 MB.
// Mask loads are non-temporal: read-once stream, keep it out of L2/L3.
// 1024 threads = 64 b-groups (float4 over batch) x 16 h-slots (2 h each).
// ---------------------------------------------------------------------------
__global__ __launch_bounds__(1024, 8) void k_layer1_split(
    const float* __restrict__ W1, const float* __restrict__ mask,
    const float* __restrict__ xT, float* __restrict__ partial)
{
    const int ht   = blockIdx.x;     // 0..31
    const int c    = blockIdx.y;     // 0..15
    const int h0   = ht * H_T;
    const int i0   = c * C_I;
    const int t    = threadIdx.x;
    const int bg   = t & 63;         // batch group: b = 4*bg..4*bg+3
    const int slot = t >> 6;         // 0..15, handles h = h0 + 2*slot + {0,1}

    __shared__ f32x4 xs[C_I][64];        // 50176 B: xs[i][bg] = xT[i0+i][4bg..]
    __shared__ float wsh[H_T][C_I];      // 6272 B:  wsh[hh][i] = W1[h0+hh][i0+i]

    // stage x chunk (coalesced float4 loads)
    {
        const f32x4* src = (const f32x4*)(xT + i0 * BATCH);
        f32x4* dst = &xs[0][0];
        for (int idx = t; idx < C_I * 64; idx += 1024)
            dst[idx] = src[idx];
    }
    // stage W1 tile
    {
        float* dst = &wsh[0][0];
        for (int idx = t; idx < H_T * C_I; idx += 1024) {
            const int hh = idx / C_I, ii = idx - hh * C_I;
            dst[idx] = W1[(h0 + hh) * IN_DIM + i0 + ii];
        }
    }
    __syncthreads();

    f32x4 acc[2];
    #pragma unroll
    for (int k = 0; k < 2; k++) {
        const int hh = slot * 2 + k;
        const int h  = h0 + hh;
        const f32x4* mrow =
            (const f32x4*)(mask + ((size_t)h * IN_DIM + i0) * BATCH) + bg;
        f32x4 a = {0.f, 0.f, 0.f, 0.f};
        #pragma unroll 2
        for (int i = 0; i < C_I; i++) {
            const f32x4 m  = __builtin_nontemporal_load(mrow + i * 64);
            const f32x4 xv = xs[i][bg];
            const float w  = wsh[hh][i];
            a.x = fmaf(w, m.x * xv.x, a.x);
            a.y = fmaf(w, m.y * xv.y, a.y);
            a.z = fmaf(w, m.z * xv.z, a.z);
            a.w = fmaf(w, m.w * xv.w, a.w);
        }
        acc[k] = a;
    }

    // partial[c][h][b] (f32x4 over b), coalesced per wave, write-once stream
    #pragma unroll
    for (int k = 0; k < 2; k++) {
        const int h = h0 + slot * 2 + k;
        __builtin_nontemporal_store(
            acc[k], (f32x4*)partial + ((size_t)c * HIDDEN + h) * 64 + bg);
    }
}

// ---------------------------------------------------------------------------
// K3: reduce the 16 partials -> h1T[h][b] = relu(b1[h] + sum_c partial)
// ---------------------------------------------------------------------------
__global__ __launch_bounds__(256) void k_reduce_h1(
    const float* __restrict__ partial, const float* __restrict__ b1,
    float* __restrict__ h1T)
{
    const int t  = threadIdx.x;
    const int bg = t & 63;
    const int h  = blockIdx.x * 4 + (t >> 6);

    const f32x4* p4 = (const f32x4*)partial;
    f32x4 s = {0.f, 0.f, 0.f, 0.f};
    #pragma unroll
    for (int cc = 0; cc < N_CH; cc++) {
        const f32x4 v = __builtin_nontemporal_load(
            p4 + ((size_t)cc * HIDDEN + h) * 64 + bg);
        s.x += v.x; s.y += v.y; s.z += v.z; s.w += v.w;
    }
    const float b = b1[h];
    f32x4 r;
    r.x = fmaxf(s.x + b, 0.f);
    r.y = fmaxf(s.y + b, 0.f);
    r.z = fmaxf(s.z + b, 0.f);
    r.w = fmaxf(s.w + b, 0.f);
    ((f32x4*)h1T)[h * 64 + bg] = r;
}

// ---------------------------------------------------------------------------
// K4: layer 2 GEMM: h2[b][j] = relu(b2[j] + sum_h h1T[h][b] * W2[j][h])
// 32x32 output tile per block, 256 blocks, 4 outputs per thread.
// ---------------------------------------------------------------------------
__global__ __launch_bounds__(256) void k_layer2(
    const float* __restrict__ h1T, const float* __restrict__ W2,
    const float* __restrict__ b2, float* __restrict__ h2)
{
    const int t  = threadIdx.x;
    const int jj = t & 31;
    const int bg = t >> 5;
    const int b0 = blockIdx.x * 32;
    const int j0 = blockIdx.y * 32;

    __shared__ __align__(16) float Ash[32][32];
    __shared__ float Bsh[32][33];

    float acc0 = 0.f, acc1 = 0.f, acc2 = 0.f, acc3 = 0.f;

    for (int h0 = 0; h0 < HIDDEN; h0 += 32) {
        #pragma unroll
        for (int r = 0; r < 4; r++) {
            const int idx = t + r * 256;
            const int hh = idx >> 5, bb = idx & 31;
            Ash[hh][bb] = h1T[(h0 + hh) * BATCH + b0 + bb];
        }
        #pragma unroll
        for (int r = 0; r < 4; r++) {
            const int idx = t + r * 256;
            const int jl = idx >> 5, hl = idx & 31;
            Bsh[hl][jl] = W2[(j0 + jl) * HIDDEN + h0 + hl];
        }
        __syncthreads();
        #pragma unroll 8
        for (int hh = 0; hh < 32; hh++) {
            const float w = Bsh[hh][jj];
            const float4 a = *(const float4*)&Ash[hh][bg * 4];
            acc0 = fmaf(a.x, w, acc0);
            acc1 = fmaf(a.y, w, acc1);
            acc2 = fmaf(a.z, w, acc2);
            acc3 = fmaf(a.w, w, acc3);
        }
        __syncthreads();
    }

    const float bias = b2[j0 + jj];
    const int base = (b0 + bg * 4) * HIDDEN + j0 + jj;
    h2[base + 0 * HIDDEN] = fmaxf(acc0 + bias, 0.f);
    h2[base + 1 * HIDDEN] = fmaxf(acc1 + bias, 0.f);
    h2[base + 2 * HIDDEN] = fmaxf(acc2 + bias, 0.f);
    h2[base + 3 * HIDDEN] = fmaxf(acc3 + bias, 0.f);
}

// ---------------------------------------------------------------------------
// K5: layer 3: out[b][o] = b3[o] + sum_h h2[b][h] * W3[o][h]
// ---------------------------------------------------------------------------
__global__ __launch_bounds__(256) void k_layer3(
    const float* __restrict__ h2, const float* __restrict__ W3,
    const float* __restrict__ b3, float* __restrict__ out)
{
    const int b = blockIdx.x;
    const int t = threadIdx.x;
    const int lane = t & 63, wid = t >> 6;

    __shared__ float hbuf[HIDDEN];
    #pragma unroll
    for (int r = 0; r < 4; r++)
        hbuf[t + r * 256] = h2[b * HIDDEN + t + r * 256];
    __syncthreads();

    float acc[OUT_DIM];
    #pragma unroll
    for (int o = 0; o < OUT_DIM; o++) acc[o] = 0.f;

    for (int h = t; h < HIDDEN; h += 256) {
        const float v = hbuf[h];
        #pragma unroll
        for (int o = 0; o < OUT_DIM; o++)
            acc[o] = fmaf(v, W3[o * HIDDEN + h], acc[o]);
    }

    __shared__ float red[4][OUT_DIM];
    #pragma unroll
    for (int o = 0; o < OUT_DIM; o++) {
        float v = acc[o];
        for (int off = 32; off > 0; off >>= 1)
            v += __shfl_down(v, off);
        if (lane == 0) red[wid][o] = v;
    }
    __syncthreads();
    if (t < OUT_DIM) {
        out[b * OUT_DIM + t] =
            red[0][t] + red[1][t] + red[2][t] + red[3][t] + b3[t];
    }
}

extern "C" void kernel_launch(void* const* d_in, const int* in_sizes, int n_in,
                              void* d_out, int out_size, void* d_ws, size_t ws_size,
                              hipStream_t stream) {
    const float* x    = (const float*)d_in[0];
    const float* mask = (const float*)d_in[1];
    const float* W1   = (const float*)d_in[2];
    const float* b1   = (const float*)d_in[3];
    const float* W2   = (const float*)d_in[4];
    const float* b2   = (const float*)d_in[5];
    const float* W3   = (const float*)d_in[6];
    const float* b3   = (const float*)d_in[7];
    float* out = (float*)d_out;

    float* ws      = (float*)d_ws;
    float* xT      = ws;                               // 784*256
    float* h1T     = xT + IN_DIM * BATCH;              // 1024*256
    float* h2      = h1T + HIDDEN * BATCH;             // 256*1024
    float* partial = h2 + BATCH * HIDDEN;              // 16*1024*256 (16 MB)

    k_transpose_x<<<IN_DIM, 256, 0, stream>>>(x, xT);
    k_layer1_split<<<dim3(HIDDEN / H_T, N_CH), 1024, 0, stream>>>(W1, mask, xT, partial);
    k_reduce_h1<<<HIDDEN / 4, 256, 0, stream>>>(partial, b1, h1T);
    k_layer2<<<dim3(BATCH / 32, HIDDEN / 32), 256, 0, stream>>>(h1T, W2, b2, h2);
    k_layer3<<<BATCH, 256, 0, stream>>>(h2, W3, b3, out);
}

// Round 3
// 1046.683 us; speedup vs baseline: 1.0356x; 1.0045x over previous
//
#include <hip/hip_runtime.h>
#include <hip/hip_bf16.h>

#define IN_DIM 784
#define HIDDEN 1024
#define OUT_DIM 10
#define BATCH 256

// layer-1 split-K tiling
#define C_I 49        // i-chunk size (784 = 16 * 49)
#define N_CH 16       // number of i-chunks
#define H_T 32        // h-tile per block

typedef float __attribute__((ext_vector_type(4))) f32x4;

// ---------------------------------------------------------------------------
// K1: transpose x [256][784] -> xT [784][256] (coalesced writes).
// ---------------------------------------------------------------------------
__global__ __launch_bounds__(256) void k_transpose_x(
    const float* __restrict__ x, float* __restrict__ xT)
{
    const int i = blockIdx.x;    // 0..783
    const int b = threadIdx.x;   // 0..255
    xT[i * BATCH + b] = x[b * IN_DIM + i];
}

// ---------------------------------------------------------------------------
// K2: DropConnect layer 1, split-K over i. Block (ht, c): h-tile of 32,
// i-chunk of 49, all 256 b. x-chunk + W1 tile in LDS. Mask loads are
// non-temporal (read-once stream; keep L2/L3 for xT/W1/partial).
// The two h-rows per slot are interleaved in the i-loop: 2x independent
// mask loads in flight, and each xs[i][bg] LDS read is shared by both.
// launch_bounds(1024,8): cap VGPRs at 64 so 2 blocks/CU co-reside
// (LDS 57 KB x 2 = 114 KB < 160 KB) -> 32 waves/CU streaming.
// ---------------------------------------------------------------------------
__global__ __launch_bounds__(1024, 8) void k_layer1_split(
    const float* __restrict__ W1, const float* __restrict__ mask,
    const float* __restrict__ xT, float* __restrict__ partial)
{
    const int ht   = blockIdx.x;     // 0..31
    const int c    = blockIdx.y;     // 0..15
    const int h0   = ht * H_T;
    const int i0   = c * C_I;
    const int t    = threadIdx.x;
    const int bg   = t & 63;         // batch group: b = 4*bg..4*bg+3
    const int slot = t >> 6;         // 0..15 -> h = h0 + 2*slot + {0,1}

    __shared__ f32x4 xs[C_I][64];        // 50176 B
    __shared__ float wsh[H_T][C_I];      // 6272 B

    // stage x chunk (coalesced f32x4 loads, L2/L3-served)
    {
        const f32x4* src = (const f32x4*)(xT + i0 * BATCH);
        f32x4* dst = &xs[0][0];
        for (int idx = t; idx < C_I * 64; idx += 1024)
            dst[idx] = src[idx];
    }
    // stage W1 tile
    {
        float* dst = &wsh[0][0];
        for (int idx = t; idx < H_T * C_I; idx += 1024) {
            const int hh = idx / C_I, ii = idx - hh * C_I;
            dst[idx] = W1[(h0 + hh) * IN_DIM + i0 + ii];
        }
    }
    __syncthreads();

    const int hh0 = slot * 2;
    const f32x4* mrow0 =
        (const f32x4*)(mask + ((size_t)(h0 + hh0) * IN_DIM + i0) * BATCH) + bg;
    const f32x4* mrow1 = mrow0 + (size_t)IN_DIM * 64;   // next h row

    f32x4 a0 = {0.f, 0.f, 0.f, 0.f};
    f32x4 a1 = {0.f, 0.f, 0.f, 0.f};
    #pragma unroll 2
    for (int i = 0; i < C_I; i++) {
        const f32x4 m0 = __builtin_nontemporal_load(mrow0 + i * 64);
        const f32x4 m1 = __builtin_nontemporal_load(mrow1 + i * 64);
        const f32x4 xv = xs[i][bg];
        const float w0 = wsh[hh0][i];
        const float w1 = wsh[hh0 + 1][i];
        a0.x = fmaf(w0, m0.x * xv.x, a0.x);
        a0.y = fmaf(w0, m0.y * xv.y, a0.y);
        a0.z = fmaf(w0, m0.z * xv.z, a0.z);
        a0.w = fmaf(w0, m0.w * xv.w, a0.w);
        a1.x = fmaf(w1, m1.x * xv.x, a1.x);
        a1.y = fmaf(w1, m1.y * xv.y, a1.y);
        a1.z = fmaf(w1, m1.z * xv.z, a1.z);
        a1.w = fmaf(w1, m1.w * xv.w, a1.w);
    }

    // partial[c][h][b]: normal (cached) stores — 16 MB, L2/L3-resident for
    // the reduce kernel; do NOT bypass caches here.
    f32x4* p4 = (f32x4*)partial + ((size_t)c * HIDDEN + h0 + hh0) * 64 + bg;
    p4[0]  = a0;
    p4[64] = a1;
}

// ---------------------------------------------------------------------------
// K3: reduce 16 partials -> h1T[h][b] = relu(b1[h] + sum_c partial)
// Cached loads: partials should be L2/L3-resident.
// ---------------------------------------------------------------------------
__global__ __launch_bounds__(256) void k_reduce_h1(
    const float* __restrict__ partial, const float* __restrict__ b1,
    float* __restrict__ h1T)
{
    const int t  = threadIdx.x;
    const int bg = t & 63;
    const int h  = blockIdx.x * 4 + (t >> 6);

    const f32x4* p4 = (const f32x4*)partial;
    f32x4 s = {0.f, 0.f, 0.f, 0.f};
    #pragma unroll
    for (int cc = 0; cc < N_CH; cc++) {
        const f32x4 v = p4[((size_t)cc * HIDDEN + h) * 64 + bg];
        s.x += v.x; s.y += v.y; s.z += v.z; s.w += v.w;
    }
    const float b = b1[h];
    f32x4 r;
    r.x = fmaxf(s.x + b, 0.f);
    r.y = fmaxf(s.y + b, 0.f);
    r.z = fmaxf(s.z + b, 0.f);
    r.w = fmaxf(s.w + b, 0.f);
    ((f32x4*)h1T)[h * 64 + bg] = r;
}

// ---------------------------------------------------------------------------
// K4: layer 2 GEMM: h2[b][j] = relu(b2[j] + sum_h h1T[h][b] * W2[j][h])
// 32x32 tile per block, grid=256 (exactly 1 block/CU, 4 waves) -> the
// staging latency is unhidden; register-double-buffered LDS staging
// overlaps tile k+1 global loads with tile k compute.
// ---------------------------------------------------------------------------
__global__ __launch_bounds__(256) void k_layer2(
    const float* __restrict__ h1T, const float* __restrict__ W2,
    const float* __restrict__ b2, float* __restrict__ h2)
{
    const int t  = threadIdx.x;
    const int jj = t & 31;
    const int bg = t >> 5;
    const int b0 = blockIdx.x * 32;
    const int j0 = blockIdx.y * 32;

    __shared__ __align__(16) float Ash[2][32][32];
    __shared__ float Bsh[2][32][33];

    // per-thread staging coords (4 elements of A, 4 of B per tile)
    int a_hh[4], a_bb[4], b_jl[4], b_hl[4];
    #pragma unroll
    for (int r = 0; r < 4; r++) {
        const int idx = t + r * 256;
        a_hh[r] = idx >> 5; a_bb[r] = idx & 31;
        b_jl[r] = idx >> 5; b_hl[r] = idx & 31;
    }

    float ra[4], rb[4];
    #pragma unroll
    for (int r = 0; r < 4; r++) {
        ra[r] = h1T[a_hh[r] * BATCH + b0 + a_bb[r]];
        rb[r] = W2[(j0 + b_jl[r]) * HIDDEN + b_hl[r]];
    }
    #pragma unroll
    for (int r = 0; r < 4; r++) {
        Ash[0][a_hh[r]][a_bb[r]] = ra[r];
        Bsh[0][b_hl[r]][b_jl[r]] = rb[r];
    }
    __syncthreads();

    float acc0 = 0.f, acc1 = 0.f, acc2 = 0.f, acc3 = 0.f;

    const int NK = HIDDEN / 32;
    for (int k = 0; k < NK; k++) {
        const int cur = k & 1;
        // issue next tile's global loads before consuming current tile
        if (k + 1 < NK) {
            const int h0n = (k + 1) * 32;
            #pragma unroll
            for (int r = 0; r < 4; r++) {
                ra[r] = h1T[(h0n + a_hh[r]) * BATCH + b0 + a_bb[r]];
                rb[r] = W2[(j0 + b_jl[r]) * HIDDEN + h0n + b_hl[r]];
            }
        }
        #pragma unroll 8
        for (int hh = 0; hh < 32; hh++) {
            const float w = Bsh[cur][hh][jj];
            const float4 a = *(const float4*)&Ash[cur][hh][bg * 4];
            acc0 = fmaf(a.x, w, acc0);
            acc1 = fmaf(a.y, w, acc1);
            acc2 = fmaf(a.z, w, acc2);
            acc3 = fmaf(a.w, w, acc3);
        }
        __syncthreads();
        if (k + 1 < NK) {
            const int nxt = cur ^ 1;
            #pragma unroll
            for (int r = 0; r < 4; r++) {
                Ash[nxt][a_hh[r]][a_bb[r]] = ra[r];
                Bsh[nxt][b_hl[r]][b_jl[r]] = rb[r];
            }
            __syncthreads();
        }
    }

    const float bias = b2[j0 + jj];
    const int base = (b0 + bg * 4) * HIDDEN + j0 + jj;
    h2[base + 0 * HIDDEN] = fmaxf(acc0 + bias, 0.f);
    h2[base + 1 * HIDDEN] = fmaxf(acc1 + bias, 0.f);
    h2[base + 2 * HIDDEN] = fmaxf(acc2 + bias, 0.f);
    h2[base + 3 * HIDDEN] = fmaxf(acc3 + bias, 0.f);
}

// ---------------------------------------------------------------------------
// K5: layer 3: out[b][o] = b3[o] + sum_h h2[b][h] * W3[o][h]
// ---------------------------------------------------------------------------
__global__ __launch_bounds__(256) void k_layer3(
    const float* __restrict__ h2, const float* __restrict__ W3,
    const float* __restrict__ b3, float* __restrict__ out)
{
    const int b = blockIdx.x;
    const int t = threadIdx.x;
    const int lane = t & 63, wid = t >> 6;

    __shared__ float hbuf[HIDDEN];
    #pragma unroll
    for (int r = 0; r < 4; r++)
        hbuf[t + r * 256] = h2[b * HIDDEN + t + r * 256];
    __syncthreads();

    float acc[OUT_DIM];
    #pragma unroll
    for (int o = 0; o < OUT_DIM; o++) acc[o] = 0.f;

    for (int h = t; h < HIDDEN; h += 256) {
        const float v = hbuf[h];
        #pragma unroll
        for (int o = 0; o < OUT_DIM; o++)
            acc[o] = fmaf(v, W3[o * HIDDEN + h], acc[o]);
    }

    __shared__ float red[4][OUT_DIM];
    #pragma unroll
    for (int o = 0; o < OUT_DIM; o++) {
        float v = acc[o];
        for (int off = 32; off > 0; off >>= 1)
            v += __shfl_down(v, off);
        if (lane == 0) red[wid][o] = v;
    }
    __syncthreads();
    if (t < OUT_DIM) {
        out[b * OUT_DIM + t] =
            red[0][t] + red[1][t] + red[2][t] + red[3][t] + b3[t];
    }
}

extern "C" void kernel_launch(void* const* d_in, const int* in_sizes, int n_in,
                              void* d_out, int out_size, void* d_ws, size_t ws_size,
                              hipStream_t stream) {
    const float* x    = (const float*)d_in[0];
    const float* mask = (const float*)d_in[1];
    const float* W1   = (const float*)d_in[2];
    const float* b1   = (const float*)d_in[3];
    const float* W2   = (const float*)d_in[4];
    const float* b2   = (const float*)d_in[5];
    const float* W3   = (const float*)d_in[6];
    const float* b3   = (const float*)d_in[7];
    float* out = (float*)d_out;

    float* ws      = (float*)d_ws;
    float* xT      = ws;                               // 784*256
    float* h1T     = xT + IN_DIM * BATCH;              // 1024*256
    float* h2      = h1T + HIDDEN * BATCH;             // 256*1024
    float* partial = h2 + BATCH * HIDDEN;              // 16*1024*256 (16 MB)

    k_transpose_x<<<IN_DIM, 256, 0, stream>>>(x, xT);
    k_layer1_split<<<dim3(HIDDEN / H_T, N_CH), 1024, 0, stream>>>(W1, mask, xT, partial);
    k_reduce_h1<<<HIDDEN / 4, 256, 0, stream>>>(partial, b1, h1T);
    k_layer2<<<dim3(BATCH / 32, HIDDEN / 32), 256, 0, stream>>>(h1T, W2, b2, h2);
    k_layer3<<<BATCH, 256, 0, stream>>>(h2, W3, b3, out);
}

// Round 4
// 1035.993 us; speedup vs baseline: 1.0462x; 1.0103x over previous
//
#include <hip/hip_runtime.h>
#include <hip/hip_bf16.h>

#define IN_DIM 784
#define HIDDEN 1024
#define OUT_DIM 10
#define BATCH 256

// layer-1 split-K tiling
#define C_I 49        // i-chunk size (784 = 16 * 49)
#define N_CH 16       // number of i-chunks
#define H_T 32        // h-tile per block

// layer-2 split-K
#define KSPLIT 4
#define KCHUNK (HIDDEN / KSPLIT)   // 256

typedef float __attribute__((ext_vector_type(4))) f32x4;

// ---------------------------------------------------------------------------
// K1: tiled transpose x [256][784] -> xT [784][256], coalesced on both sides.
// Block (it, bt): 32x32 tile, 256 threads = 32 lanes x 8 rows.
// ---------------------------------------------------------------------------
__global__ __launch_bounds__(256) void k_transpose_x(
    const float* __restrict__ x, float* __restrict__ xT)
{
    __shared__ float tile[32][33];
    const int tx = threadIdx.x & 31;
    const int ty = threadIdx.x >> 5;       // 0..7
    const int i0 = blockIdx.x * 32;        // 0..768 (25 blocks, last half-valid)
    const int b0 = blockIdx.y * 32;

    #pragma unroll
    for (int r = 0; r < 4; r++) {
        const int bb = ty + r * 8;
        const int i  = i0 + tx;
        tile[bb][tx] = (i < IN_DIM) ? x[(b0 + bb) * IN_DIM + i] : 0.f;
    }
    __syncthreads();
    #pragma unroll
    for (int r = 0; r < 4; r++) {
        const int ii = ty + r * 8;
        if (i0 + ii < IN_DIM)
            xT[(i0 + ii) * BATCH + b0 + tx] = tile[tx][ii];
    }
}

// ---------------------------------------------------------------------------
// K2: DropConnect layer 1, split-K over i (unchanged — measured neutral to
// tweak; mask stream is the HBM-roofline component).
// ---------------------------------------------------------------------------
__global__ __launch_bounds__(1024, 8) void k_layer1_split(
    const float* __restrict__ W1, const float* __restrict__ mask,
    const float* __restrict__ xT, float* __restrict__ partial)
{
    const int ht   = blockIdx.x;     // 0..31
    const int c    = blockIdx.y;     // 0..15
    const int h0   = ht * H_T;
    const int i0   = c * C_I;
    const int t    = threadIdx.x;
    const int bg   = t & 63;         // batch group: b = 4*bg..4*bg+3
    const int slot = t >> 6;         // 0..15 -> h = h0 + 2*slot + {0,1}

    __shared__ f32x4 xs[C_I][64];        // 50176 B
    __shared__ float wsh[H_T][C_I];      // 6272 B

    {
        const f32x4* src = (const f32x4*)(xT + i0 * BATCH);
        f32x4* dst = &xs[0][0];
        for (int idx = t; idx < C_I * 64; idx += 1024)
            dst[idx] = src[idx];
    }
    {
        float* dst = &wsh[0][0];
        for (int idx = t; idx < H_T * C_I; idx += 1024) {
            const int hh = idx / C_I, ii = idx - hh * C_I;
            dst[idx] = W1[(h0 + hh) * IN_DIM + i0 + ii];
        }
    }
    __syncthreads();

    const int hh0 = slot * 2;
    const f32x4* mrow0 =
        (const f32x4*)(mask + ((size_t)(h0 + hh0) * IN_DIM + i0) * BATCH) + bg;
    const f32x4* mrow1 = mrow0 + (size_t)IN_DIM * 64;

    f32x4 a0 = {0.f, 0.f, 0.f, 0.f};
    f32x4 a1 = {0.f, 0.f, 0.f, 0.f};
    #pragma unroll 2
    for (int i = 0; i < C_I; i++) {
        const f32x4 m0 = __builtin_nontemporal_load(mrow0 + i * 64);
        const f32x4 m1 = __builtin_nontemporal_load(mrow1 + i * 64);
        const f32x4 xv = xs[i][bg];
        const float w0 = wsh[hh0][i];
        const float w1 = wsh[hh0 + 1][i];
        a0.x = fmaf(w0, m0.x * xv.x, a0.x);
        a0.y = fmaf(w0, m0.y * xv.y, a0.y);
        a0.z = fmaf(w0, m0.z * xv.z, a0.z);
        a0.w = fmaf(w0, m0.w * xv.w, a0.w);
        a1.x = fmaf(w1, m1.x * xv.x, a1.x);
        a1.y = fmaf(w1, m1.y * xv.y, a1.y);
        a1.z = fmaf(w1, m1.z * xv.z, a1.z);
        a1.w = fmaf(w1, m1.w * xv.w, a1.w);
    }

    f32x4* p4 = (f32x4*)partial + ((size_t)c * HIDDEN + h0 + hh0) * 64 + bg;
    p4[0]  = a0;
    p4[64] = a1;
}

// ---------------------------------------------------------------------------
// K3: reduce 16 partials -> h1T[h][b] = relu(b1[h] + sum_c partial)
// ---------------------------------------------------------------------------
__global__ __launch_bounds__(256) void k_reduce_h1(
    const float* __restrict__ partial, const float* __restrict__ b1,
    float* __restrict__ h1T)
{
    const int t  = threadIdx.x;
    const int bg = t & 63;
    const int h  = blockIdx.x * 4 + (t >> 6);

    const f32x4* p4 = (const f32x4*)partial;
    f32x4 s = {0.f, 0.f, 0.f, 0.f};
    #pragma unroll
    for (int cc = 0; cc < N_CH; cc++) {
        const f32x4 v = p4[((size_t)cc * HIDDEN + h) * 64 + bg];
        s.x += v.x; s.y += v.y; s.z += v.z; s.w += v.w;
    }
    const float b = b1[h];
    f32x4 r;
    r.x = fmaxf(s.x + b, 0.f);
    r.y = fmaxf(s.y + b, 0.f);
    r.z = fmaxf(s.z + b, 0.f);
    r.w = fmaxf(s.w + b, 0.f);
    ((f32x4*)h1T)[h * 64 + bg] = r;
}

// ---------------------------------------------------------------------------
// K4: layer 2 GEMM, split-K x4:
//   h2p[kc][b][j] = sum_{h in kc-chunk} h1T[h][b] * W2[j][h]
// Grid (8 b-tiles, 32 j-tiles, 4 k-chunks) = 1024 blocks -> 4 blocks/CU,
// 16 waves/CU; each block runs only 8 barrier-separated sub-tiles (was 32).
// No bias/relu here — layer 3 fuses the 4-way reduction + bias + relu.
// ---------------------------------------------------------------------------
__global__ __launch_bounds__(256) void k_layer2_split(
    const float* __restrict__ h1T, const float* __restrict__ W2,
    float* __restrict__ h2p)
{
    const int t  = threadIdx.x;
    const int jj = t & 31;
    const int bg = t >> 5;
    const int b0 = blockIdx.x * 32;
    const int j0 = blockIdx.y * 32;
    const int hbase = blockIdx.z * KCHUNK;

    __shared__ __align__(16) float Ash[32][32];
    __shared__ float Bsh[32][33];

    float acc0 = 0.f, acc1 = 0.f, acc2 = 0.f, acc3 = 0.f;

    for (int s = 0; s < KCHUNK; s += 32) {
        const int h0 = hbase + s;
        #pragma unroll
        for (int r = 0; r < 4; r++) {
            const int idx = t + r * 256;
            const int hh = idx >> 5, bb = idx & 31;
            Ash[hh][bb] = h1T[(h0 + hh) * BATCH + b0 + bb];
        }
        #pragma unroll
        for (int r = 0; r < 4; r++) {
            const int idx = t + r * 256;
            const int jl = idx >> 5, hl = idx & 31;
            Bsh[hl][jl] = W2[(j0 + jl) * HIDDEN + h0 + hl];
        }
        __syncthreads();
        #pragma unroll 8
        for (int hh = 0; hh < 32; hh++) {
            const float w = Bsh[hh][jj];
            const float4 a = *(const float4*)&Ash[hh][bg * 4];
            acc0 = fmaf(a.x, w, acc0);
            acc1 = fmaf(a.y, w, acc1);
            acc2 = fmaf(a.z, w, acc2);
            acc3 = fmaf(a.w, w, acc3);
        }
        __syncthreads();
    }

    float* dst = h2p + (size_t)blockIdx.z * (BATCH * HIDDEN);
    const int base = (b0 + bg * 4) * HIDDEN + j0 + jj;
    dst[base + 0 * HIDDEN] = acc0;
    dst[base + 1 * HIDDEN] = acc1;
    dst[base + 2 * HIDDEN] = acc2;
    dst[base + 3 * HIDDEN] = acc3;
}

// ---------------------------------------------------------------------------
// K5: layer 3, fused with layer-2 k-split reduction + bias + relu:
//   h2[b][h] = relu(b2[h] + sum_kc h2p[kc][b][h])   (in LDS only)
//   out[b][o] = b3[o] + sum_h h2[b][h] * W3[o][h]
// ---------------------------------------------------------------------------
__global__ __launch_bounds__(256) void k_layer3(
    const float* __restrict__ h2p, const float* __restrict__ W3,
    const float* __restrict__ b2, const float* __restrict__ b3,
    float* __restrict__ out)
{
    const int b = blockIdx.x;
    const int t = threadIdx.x;
    const int lane = t & 63, wid = t >> 6;

    __shared__ float hbuf[HIDDEN];
    #pragma unroll
    for (int r = 0; r < 4; r++) {
        const int h = t + r * 256;
        float v = b2[h];
        #pragma unroll
        for (int kc = 0; kc < KSPLIT; kc++)
            v += h2p[(size_t)kc * (BATCH * HIDDEN) + b * HIDDEN + h];
        hbuf[h] = fmaxf(v, 0.f);
    }
    __syncthreads();

    float acc[OUT_DIM];
    #pragma unroll
    for (int o = 0; o < OUT_DIM; o++) acc[o] = 0.f;

    for (int h = t; h < HIDDEN; h += 256) {
        const float v = hbuf[h];
        #pragma unroll
        for (int o = 0; o < OUT_DIM; o++)
            acc[o] = fmaf(v, W3[o * HIDDEN + h], acc[o]);
    }

    __shared__ float red[4][OUT_DIM];
    #pragma unroll
    for (int o = 0; o < OUT_DIM; o++) {
        float v = acc[o];
        for (int off = 32; off > 0; off >>= 1)
            v += __shfl_down(v, off);
        if (lane == 0) red[wid][o] = v;
    }
    __syncthreads();
    if (t < OUT_DIM) {
        out[b * OUT_DIM + t] =
            red[0][t] + red[1][t] + red[2][t] + red[3][t] + b3[t];
    }
}

extern "C" void kernel_launch(void* const* d_in, const int* in_sizes, int n_in,
                              void* d_out, int out_size, void* d_ws, size_t ws_size,
                              hipStream_t stream) {
    const float* x    = (const float*)d_in[0];
    const float* mask = (const float*)d_in[1];
    const float* W1   = (const float*)d_in[2];
    const float* b1   = (const float*)d_in[3];
    const float* W2   = (const float*)d_in[4];
    const float* b2   = (const float*)d_in[5];
    const float* W3   = (const float*)d_in[6];
    const float* b3   = (const float*)d_in[7];
    float* out = (float*)d_out;

    float* ws      = (float*)d_ws;
    float* xT      = ws;                               // 784*256
    float* h1T     = xT + IN_DIM * BATCH;              // 1024*256
    float* h2p     = h1T + HIDDEN * BATCH;             // 4*256*1024 (4 MB)
    float* partial = h2p + KSPLIT * BATCH * HIDDEN;    // 16*1024*256 (16 MB)

    k_transpose_x<<<dim3(25, BATCH / 32), 256, 0, stream>>>(x, xT);
    k_layer1_split<<<dim3(HIDDEN / H_T, N_CH), 1024, 0, stream>>>(W1, mask, xT, partial);
    k_reduce_h1<<<HIDDEN / 4, 256, 0, stream>>>(partial, b1, h1T);
    k_layer2_split<<<dim3(BATCH / 32, HIDDEN / 32, KSPLIT), 256, 0, stream>>>(h1T, W2, h2p);
    k_layer3<<<BATCH, 256, 0, stream>>>(h2p, W3, b2, b3, out);
}